// Round 2
// baseline (316.308 us; speedup 1.0000x reference)
//
#include <hip/hip_runtime.h>

#define QD 512
#define KD 64
#define NR 32     // rows per block
#define LDA 136   // lds_A row stride in shorts (128 + 8 pad)
#define LDT 68    // lds_t row stride in floats (64 + 4 pad) — aliases lds_A (same bytes)
#define LDU 72    // lds_u row stride in shorts (64 + 8 pad)

typedef __attribute__((ext_vector_type(8))) short short8;
typedef __attribute__((ext_vector_type(4))) float f32x4;
typedef __attribute__((ext_vector_type(4))) unsigned short u16x4;

static __device__ __forceinline__ unsigned short f2bf(float f) {
  unsigned u = __builtin_bit_cast(unsigned, f);
  u += 0x7FFFu + ((u >> 16) & 1u);   // round-to-nearest-even
  return (unsigned short)(u >> 16);
}
static __device__ __forceinline__ float bf2f(unsigned short s) {
  return __builtin_bit_cast(float, (unsigned)s << 16);
}
static __device__ __forceinline__ short8 pack8(f32x4 a, f32x4 b) {
  short8 r;
  r[0] = (short)f2bf(a[0]); r[1] = (short)f2bf(a[1]);
  r[2] = (short)f2bf(a[2]); r[3] = (short)f2bf(a[3]);
  r[4] = (short)f2bf(b[0]); r[5] = (short)f2bf(b[1]);
  r[6] = (short)f2bf(b[2]); r[7] = (short)f2bf(b[3]);
  return r;
}

// Prep: M^T[c][d] = sum_e w_q[e,d]*w_k[e,c]  (bf16), plus w_v cast to bf16.
__global__ __launch_bounds__(256) void prep_kernel(
    const float* __restrict__ w_q, const float* __restrict__ w_k,
    const float* __restrict__ w_v, unsigned short* __restrict__ mt,
    unsigned short* __restrict__ wvb) {
  const int tid = (int)(blockIdx.x * 256 + threadIdx.x);
  if (tid < QD * KD) {
    const int c = tid >> 9;      // 0..63
    const int d = tid & 511;     // 0..511
    float acc = 0.f;
#pragma unroll 8
    for (int e = 0; e < 64; ++e)
      acc = fmaf(w_q[e * QD + d], w_k[e * KD + c], acc);
    mt[c * QD + d] = f2bf(acc);
  } else {
    const int i = tid - QD * KD;
    if (i < KD * KD) wvb[i] = f2bf(w_v[i]);
  }
}

__global__ __launch_bounds__(256, 6) void fused_kernel(
    const float* __restrict__ query,
    const float* __restrict__ kv,
    const unsigned short* __restrict__ mt,
    const unsigned short* __restrict__ wvb,
    const float* __restrict__ gamma,
    const float* __restrict__ beta,
    float* __restrict__ out) {
  // lds_A (bf16 query tile) and lds_t (fp32 t/o tile) have disjoint lifetimes
  // separated by __syncthreads — alias them. 8704 B each.
  __shared__ char shbuf[NR * LDA * 2];
  unsigned short* lds_A = (unsigned short*)shbuf;
  float* lds_t = (float*)shbuf;
  __shared__ unsigned short lds_u[NR * LDU];   // 4608 B. Total LDS = 13312 B.

  const int tid  = (int)threadIdx.x;
  const int w    = tid >> 6;       // wave 0..3 -> col-tile of 16
  const int l    = tid & 63;
  const int m    = l & 15;
  const int quad = l >> 4;
  const long b0  = (long)blockIdx.x * NR;

  // ---- B fragments of M^T for this wave's 16 output dims (held in VGPRs) ----
  short8 bfrag[16];
  {
    const unsigned short* mp = mt + (w * 16 + m) * QD + quad * 8;
#pragma unroll
    for (int ks = 0; ks < 16; ++ks)
      bfrag[ks] = *(const short8*)(mp + ks * 32);
  }

  f32x4 acc[2];
  acc[0] = (f32x4){0.f, 0.f, 0.f, 0.f};
  acc[1] = (f32x4){0.f, 0.f, 0.f, 0.f};

  // ---- GEMM1: t = query_tile @ M, K=512 in 4 chunks of 128, prefetched ----
  const int srow = tid >> 3;   // 0..31
  const int cseg = tid & 7;    // 0..7, 16 k's each per chunk
  const float* qbase = query + (b0 + srow) * QD + cseg * 16;
  unsigned short* abase = lds_A + srow * LDA + cseg * 16;

  f32x4 stg[4];
#pragma unroll
  for (int i = 0; i < 4; ++i) stg[i] = *(const f32x4*)(qbase + i * 4);

#pragma unroll
  for (int kc = 0; kc < 4; ++kc) {
#pragma unroll
    for (int i = 0; i < 4; ++i)
      *(u16x4*)(abase + i * 4) = (u16x4){f2bf(stg[i][0]), f2bf(stg[i][1]),
                                         f2bf(stg[i][2]), f2bf(stg[i][3])};
    __syncthreads();
    if (kc < 3) {
      const float* nq = qbase + (kc + 1) * 128;
#pragma unroll
      for (int i = 0; i < 4; ++i) stg[i] = *(const f32x4*)(nq + i * 4);
    }
#pragma unroll
    for (int ks2 = 0; ks2 < 4; ++ks2) {
#pragma unroll
      for (int rt = 0; rt < 2; ++rt) {
        short8 af = *(const short8*)(lds_A + (rt * 16 + m) * LDA + ks2 * 32 + quad * 8);
        acc[rt] = __builtin_amdgcn_mfma_f32_16x16x32_bf16(af, bfrag[kc * 4 + ks2],
                                                          acc[rt], 0, 0, 0);
      }
    }
    __syncthreads();
  }

  // ---- write t to LDS (C layout: col=lane&15, row=quad*4+reg) ----
  // Safe to alias lds_A: last MFMA read is before the final barrier above.
#pragma unroll
  for (int rt = 0; rt < 2; ++rt)
#pragma unroll
    for (int r2 = 0; r2 < 4; ++r2)
      lds_t[(rt * 16 + quad * 4 + r2) * LDT + w * 16 + m] = acc[rt][r2];
  __syncthreads();

  // ---- per-row attention: 8 threads per row, 8 dims per thread ----
  const int rl = w * 8 + (l >> 3);   // row 0..31
  const int o8 = l & 7;              // dim segment
  const int db = o8 * 8;             // dim base
  const long brow = b0 + rl;

  const float* tp = lds_t + rl * LDT + db;
  f32x4 tv0 = ((const f32x4*)tp)[0];
  f32x4 tv1 = ((const f32x4*)tp)[1];

  float s[8];
  short8 kvb[8];
#pragma unroll
  for (int n = 0; n < 8; ++n) {
    const float* kp = kv + (brow * 8 + n) * 64 + db;
    f32x4 k0 = ((const f32x4*)kp)[0];
    f32x4 k1 = ((const f32x4*)kp)[1];
    f32x4 d = tv0 * k0 + tv1 * k1;
    s[n] = d[0] + d[1] + d[2] + d[3];
    kvb[n] = pack8(k0, k1);           // hold kv as bf16 for the u pass
  }
#pragma unroll
  for (int n = 0; n < 8; ++n) {       // reduce partials across the 8 dim-lanes
    s[n] += __shfl_xor(s[n], 1, 64);
    s[n] += __shfl_xor(s[n], 2, 64);
    s[n] += __shfl_xor(s[n], 4, 64);
  }
  float mx = s[0];
#pragma unroll
  for (int n = 1; n < 8; ++n) mx = fmaxf(mx, s[n]);
  float ev[8];
  float esum = 0.f;
#pragma unroll
  for (int n = 0; n < 8; ++n) { ev[n] = __expf((s[n] - mx) * 0.125f); esum += ev[n]; }
  const float rinv = 1.0f / esum;

  f32x4 u0 = {0.f, 0.f, 0.f, 0.f}, u1 = u0;
#pragma unroll
  for (int n = 0; n < 8; ++n) {
    const float a = ev[n];
    short8 p = kvb[n];
    u0 += a * (f32x4){bf2f((unsigned short)p[0]), bf2f((unsigned short)p[1]),
                      bf2f((unsigned short)p[2]), bf2f((unsigned short)p[3])};
    u1 += a * (f32x4){bf2f((unsigned short)p[4]), bf2f((unsigned short)p[5]),
                      bf2f((unsigned short)p[6]), bf2f((unsigned short)p[7])};
  }
  u0 *= rinv; u1 *= rinv;
  *(short8*)(lds_u + rl * LDU + db) = pack8(u0, u1);
  __syncthreads();

  // ---- GEMM2: o = u @ w_v^T (K=64, 2 MFMA k-steps) ----
  short8 wvf0 = *(const short8*)(wvb + (w * 16 + m) * 64 + quad * 8);
  short8 wvf1 = *(const short8*)(wvb + (w * 16 + m) * 64 + 32 + quad * 8);
  f32x4 o[2];
  o[0] = (f32x4){0.f, 0.f, 0.f, 0.f};
  o[1] = (f32x4){0.f, 0.f, 0.f, 0.f};
#pragma unroll
  for (int rt = 0; rt < 2; ++rt) {
    short8 a0 = *(const short8*)(lds_u + (rt * 16 + m) * LDU + quad * 8);
    o[rt] = __builtin_amdgcn_mfma_f32_16x16x32_bf16(a0, wvf0, o[rt], 0, 0, 0);
    short8 a1 = *(const short8*)(lds_u + (rt * 16 + m) * LDU + 32 + quad * 8);
    o[rt] = __builtin_amdgcn_mfma_f32_16x16x32_bf16(a1, wvf1, o[rt], 0, 0, 0);
  }
  // write o into lds_t (safe: all tv reads completed before the u barrier)
#pragma unroll
  for (int rt = 0; rt < 2; ++rt)
#pragma unroll
    for (int r2 = 0; r2 < 4; ++r2)
      lds_t[(rt * 16 + quad * 4 + r2) * LDT + w * 16 + m] = o[rt][r2];
  __syncthreads();

  // ---- LayerNorm over 64 dims (8 lanes per row) ----
  const float* op = lds_t + rl * LDT + db;
  f32x4 x0 = ((const f32x4*)op)[0];
  f32x4 x1 = ((const f32x4*)op)[1];
  f32x4 sv = x0 + x1;
  f32x4 sq = x0 * x0 + x1 * x1;
  float s1 = sv[0] + sv[1] + sv[2] + sv[3];
  float s2 = sq[0] + sq[1] + sq[2] + sq[3];
  s1 += __shfl_xor(s1, 1, 64); s1 += __shfl_xor(s1, 2, 64); s1 += __shfl_xor(s1, 4, 64);
  s2 += __shfl_xor(s2, 1, 64); s2 += __shfl_xor(s2, 2, 64); s2 += __shfl_xor(s2, 4, 64);
  const float mu   = s1 * 0.015625f;
  const float var  = s2 * 0.015625f - mu * mu;
  const float rstd = rsqrtf(var + 1e-5f);
  const float* gp = gamma + db;
  const float* bp = beta + db;
  float* dst = out + brow * 64 + db;
  {
    f32x4 g0 = ((const f32x4*)gp)[0], g1 = ((const f32x4*)gp)[1];
    f32x4 e0 = ((const f32x4*)bp)[0], e1 = ((const f32x4*)bp)[1];
    ((f32x4*)dst)[0] = (x0 - mu) * rstd * g0 + e0;
    ((f32x4*)dst)[1] = (x1 - mu) * rstd * g1 + e1;
  }
}

extern "C" void kernel_launch(void* const* d_in, const int* in_sizes, int n_in,
                              void* d_out, int out_size, void* d_ws, size_t ws_size,
                              hipStream_t stream) {
  const float* query = (const float*)d_in[0];
  const float* kv    = (const float*)d_in[1];
  const float* w_q   = (const float*)d_in[2];
  const float* w_k   = (const float*)d_in[3];
  const float* w_v   = (const float*)d_in[4];
  const float* gamma = (const float*)d_in[5];
  const float* beta  = (const float*)d_in[6];
  float* out = (float*)d_out;

  unsigned short* mt  = (unsigned short*)d_ws;   // 512*64 bf16
  unsigned short* wvb = mt + QD * KD;            // 64*64 bf16

  const int Bn = in_sizes[0] / QD;               // 65536

  prep_kernel<<<(QD * KD + KD * KD + 255) / 256, 256, 0, stream>>>(w_q, w_k, w_v, mt, wvb);
  fused_kernel<<<Bn / NR, 256, 0, stream>>>(query, kv, mt, wvb, gamma, beta, out);
}

// Round 3
// 300.713 us; speedup vs baseline: 1.0519x; 1.0519x over previous
//
#include <hip/hip_runtime.h>

#define QD 512
#define KD 64
#define NR 32     // rows per block
#define LDA 136   // lds_A row stride in shorts (128 + 8 pad)
#define LDT 68    // lds_t row stride in floats (64 + 4 pad) — aliases lds_A (same bytes)
#define LDU 72    // lds_u row stride in shorts (64 + 8 pad)

typedef __attribute__((ext_vector_type(8))) short short8;
typedef __attribute__((ext_vector_type(4))) float f32x4;
typedef __attribute__((ext_vector_type(4))) unsigned short u16x4;

static __device__ __forceinline__ unsigned short f2bf(float f) {
  unsigned u = __builtin_bit_cast(unsigned, f);
  u += 0x7FFFu + ((u >> 16) & 1u);   // round-to-nearest-even
  return (unsigned short)(u >> 16);
}
static __device__ __forceinline__ float bf2f(unsigned short s) {
  return __builtin_bit_cast(float, (unsigned)s << 16);
}
static __device__ __forceinline__ short8 pack8(f32x4 a, f32x4 b) {
  short8 r;
  r[0] = (short)f2bf(a[0]); r[1] = (short)f2bf(a[1]);
  r[2] = (short)f2bf(a[2]); r[3] = (short)f2bf(a[3]);
  r[4] = (short)f2bf(b[0]); r[5] = (short)f2bf(b[1]);
  r[6] = (short)f2bf(b[2]); r[7] = (short)f2bf(b[3]);
  return r;
}

// Prep: M^T[c][d] = sum_e w_q[e,d]*w_k[e,c]  (bf16), plus w_v cast to bf16.
__global__ __launch_bounds__(256) void prep_kernel(
    const float* __restrict__ w_q, const float* __restrict__ w_k,
    const float* __restrict__ w_v, unsigned short* __restrict__ mt,
    unsigned short* __restrict__ wvb) {
  const int tid = (int)(blockIdx.x * 256 + threadIdx.x);
  if (tid < QD * KD) {
    const int c = tid >> 9;      // 0..63
    const int d = tid & 511;     // 0..511
    float acc = 0.f;
#pragma unroll 8
    for (int e = 0; e < 64; ++e)
      acc = fmaf(w_q[e * QD + d], w_k[e * KD + c], acc);
    mt[c * QD + d] = f2bf(acc);
  } else {
    const int i = tid - QD * KD;
    if (i < KD * KD) wvb[i] = f2bf(w_v[i]);
  }
}

__global__ __launch_bounds__(256, 6) void fused_kernel(
    const float* __restrict__ query,
    const float* __restrict__ kv,
    const unsigned short* __restrict__ mt,
    const unsigned short* __restrict__ wvb,
    const float* __restrict__ gamma,
    const float* __restrict__ beta,
    float* __restrict__ out) {
  // lds_A (bf16 query tile) and lds_t (fp32 t/o tile) have disjoint lifetimes
  // separated by __syncthreads — alias them. 8704 B each.
  __shared__ char shbuf[NR * LDA * 2];
  unsigned short* lds_A = (unsigned short*)shbuf;
  float* lds_t = (float*)shbuf;
  __shared__ unsigned short lds_u[NR * LDU];   // 4608 B. Total LDS = 13312 B.

  const int tid  = (int)threadIdx.x;
  const int w    = tid >> 6;       // wave 0..3 -> col-tile of 16
  const int l    = tid & 63;
  const int m    = l & 15;
  const int quad = l >> 4;
  const long b0  = (long)blockIdx.x * NR;

  // ---- B fragments of M^T: double-buffered 4-at-a-time along K chunks.
  // (Round-2 bug: holding all 16 (64 VGPRs) spilled to scratch under the
  //  85-reg cap — 75 MB of spurious HBM write traffic. Keep only 2x4.)
  const unsigned short* mrow = mt + (w * 16 + m) * QD + quad * 8;
  short8 bf_cur[4], bf_nxt[4];
#pragma unroll
  for (int ks = 0; ks < 4; ++ks)
    bf_cur[ks] = *(const short8*)(mrow + ks * 32);

  f32x4 acc[2];
  acc[0] = (f32x4){0.f, 0.f, 0.f, 0.f};
  acc[1] = (f32x4){0.f, 0.f, 0.f, 0.f};

  // ---- GEMM1: t = query_tile @ M, K=512 in 4 chunks of 128, prefetched ----
  const int srow = tid >> 3;   // 0..31
  const int cseg = tid & 7;    // 0..7, 16 k's each per chunk
  const float* qbase = query + (b0 + srow) * QD + cseg * 16;
  unsigned short* abase = lds_A + srow * LDA + cseg * 16;

  f32x4 stg[4];
#pragma unroll
  for (int i = 0; i < 4; ++i) stg[i] = *(const f32x4*)(qbase + i * 4);

#pragma unroll
  for (int kc = 0; kc < 4; ++kc) {
#pragma unroll
    for (int i = 0; i < 4; ++i)
      *(u16x4*)(abase + i * 4) = (u16x4){f2bf(stg[i][0]), f2bf(stg[i][1]),
                                         f2bf(stg[i][2]), f2bf(stg[i][3])};
    __syncthreads();
    if (kc < 3) {
      const float* nq = qbase + (kc + 1) * 128;
#pragma unroll
      for (int i = 0; i < 4; ++i) stg[i] = *(const f32x4*)(nq + i * 4);
      const unsigned short* mn = mrow + (kc + 1) * 128;
#pragma unroll
      for (int ks = 0; ks < 4; ++ks)
        bf_nxt[ks] = *(const short8*)(mn + ks * 32);
    }
#pragma unroll
    for (int ks2 = 0; ks2 < 4; ++ks2) {
#pragma unroll
      for (int rt = 0; rt < 2; ++rt) {
        short8 af = *(const short8*)(lds_A + (rt * 16 + m) * LDA + ks2 * 32 + quad * 8);
        acc[rt] = __builtin_amdgcn_mfma_f32_16x16x32_bf16(af, bf_cur[ks2],
                                                          acc[rt], 0, 0, 0);
      }
    }
    __syncthreads();
    if (kc < 3) {
#pragma unroll
      for (int ks = 0; ks < 4; ++ks) bf_cur[ks] = bf_nxt[ks];
    }
  }

  // ---- write t to LDS (C layout: col=lane&15, row=quad*4+reg) ----
  // Safe to alias lds_A: last MFMA read is before the final barrier above.
#pragma unroll
  for (int rt = 0; rt < 2; ++rt)
#pragma unroll
    for (int r2 = 0; r2 < 4; ++r2)
      lds_t[(rt * 16 + quad * 4 + r2) * LDT + w * 16 + m] = acc[rt][r2];
  __syncthreads();

  // ---- per-row attention: 8 threads per row, 8 dims per thread ----
  const int rl = w * 8 + (l >> 3);   // row 0..31
  const int o8 = l & 7;              // dim segment
  const int db = o8 * 8;             // dim base
  const long brow = b0 + rl;

  const float* tp = lds_t + rl * LDT + db;
  f32x4 tv0 = ((const f32x4*)tp)[0];
  f32x4 tv1 = ((const f32x4*)tp)[1];

  float s[8];
  short8 kvb[8];
#pragma unroll
  for (int n = 0; n < 8; ++n) {
    const float* kp = kv + (brow * 8 + n) * 64 + db;
    f32x4 k0 = ((const f32x4*)kp)[0];
    f32x4 k1 = ((const f32x4*)kp)[1];
    f32x4 d = tv0 * k0 + tv1 * k1;
    s[n] = d[0] + d[1] + d[2] + d[3];
    kvb[n] = pack8(k0, k1);           // hold kv as bf16 for the u pass
  }
#pragma unroll
  for (int n = 0; n < 8; ++n) {       // reduce partials across the 8 dim-lanes
    s[n] += __shfl_xor(s[n], 1, 64);
    s[n] += __shfl_xor(s[n], 2, 64);
    s[n] += __shfl_xor(s[n], 4, 64);
  }
  float mx = s[0];
#pragma unroll
  for (int n = 1; n < 8; ++n) mx = fmaxf(mx, s[n]);
  float ev[8];
  float esum = 0.f;
#pragma unroll
  for (int n = 0; n < 8; ++n) { ev[n] = __expf((s[n] - mx) * 0.125f); esum += ev[n]; }
  const float rinv = 1.0f / esum;

  f32x4 u0 = {0.f, 0.f, 0.f, 0.f}, u1 = u0;
#pragma unroll
  for (int n = 0; n < 8; ++n) {
    const float a = ev[n];
    short8 p = kvb[n];
    u0 += a * (f32x4){bf2f((unsigned short)p[0]), bf2f((unsigned short)p[1]),
                      bf2f((unsigned short)p[2]), bf2f((unsigned short)p[3])};
    u1 += a * (f32x4){bf2f((unsigned short)p[4]), bf2f((unsigned short)p[5]),
                      bf2f((unsigned short)p[6]), bf2f((unsigned short)p[7])};
  }
  u0 *= rinv; u1 *= rinv;
  *(short8*)(lds_u + rl * LDU + db) = pack8(u0, u1);
  __syncthreads();

  // ---- GEMM2: o = u @ w_v^T (K=64, 2 MFMA k-steps) ----
  short8 wvf0 = *(const short8*)(wvb + (w * 16 + m) * 64 + quad * 8);
  short8 wvf1 = *(const short8*)(wvb + (w * 16 + m) * 64 + 32 + quad * 8);
  f32x4 o[2];
  o[0] = (f32x4){0.f, 0.f, 0.f, 0.f};
  o[1] = (f32x4){0.f, 0.f, 0.f, 0.f};
#pragma unroll
  for (int rt = 0; rt < 2; ++rt) {
    short8 a0 = *(const short8*)(lds_u + (rt * 16 + m) * LDU + quad * 8);
    o[rt] = __builtin_amdgcn_mfma_f32_16x16x32_bf16(a0, wvf0, o[rt], 0, 0, 0);
    short8 a1 = *(const short8*)(lds_u + (rt * 16 + m) * LDU + 32 + quad * 8);
    o[rt] = __builtin_amdgcn_mfma_f32_16x16x32_bf16(a1, wvf1, o[rt], 0, 0, 0);
  }
  // write o into lds_t (safe: all tv reads completed before the u barrier)
#pragma unroll
  for (int rt = 0; rt < 2; ++rt)
#pragma unroll
    for (int r2 = 0; r2 < 4; ++r2)
      lds_t[(rt * 16 + quad * 4 + r2) * LDT + w * 16 + m] = o[rt][r2];
  __syncthreads();

  // ---- LayerNorm over 64 dims (8 lanes per row) ----
  const float* op = lds_t + rl * LDT + db;
  f32x4 x0 = ((const f32x4*)op)[0];
  f32x4 x1 = ((const f32x4*)op)[1];
  f32x4 sv = x0 + x1;
  f32x4 sq = x0 * x0 + x1 * x1;
  float s1 = sv[0] + sv[1] + sv[2] + sv[3];
  float s2 = sq[0] + sq[1] + sq[2] + sq[3];
  s1 += __shfl_xor(s1, 1, 64); s1 += __shfl_xor(s1, 2, 64); s1 += __shfl_xor(s1, 4, 64);
  s2 += __shfl_xor(s2, 1, 64); s2 += __shfl_xor(s2, 2, 64); s2 += __shfl_xor(s2, 4, 64);
  const float mu   = s1 * 0.015625f;
  const float var  = s2 * 0.015625f - mu * mu;
  const float rstd = rsqrtf(var + 1e-5f);
  const float* gp = gamma + db;
  const float* bp = beta + db;
  float* dst = out + brow * 64 + db;
  {
    f32x4 g0 = ((const f32x4*)gp)[0], g1 = ((const f32x4*)gp)[1];
    f32x4 e0 = ((const f32x4*)bp)[0], e1 = ((const f32x4*)bp)[1];
    ((f32x4*)dst)[0] = (x0 - mu) * rstd * g0 + e0;
    ((f32x4*)dst)[1] = (x1 - mu) * rstd * g1 + e1;
  }
}

extern "C" void kernel_launch(void* const* d_in, const int* in_sizes, int n_in,
                              void* d_out, int out_size, void* d_ws, size_t ws_size,
                              hipStream_t stream) {
  const float* query = (const float*)d_in[0];
  const float* kv    = (const float*)d_in[1];
  const float* w_q   = (const float*)d_in[2];
  const float* w_k   = (const float*)d_in[3];
  const float* w_v   = (const float*)d_in[4];
  const float* gamma = (const float*)d_in[5];
  const float* beta  = (const float*)d_in[6];
  float* out = (float*)d_out;

  unsigned short* mt  = (unsigned short*)d_ws;   // 512*64 bf16
  unsigned short* wvb = mt + QD * KD;            // 64*64 bf16

  const int Bn = in_sizes[0] / QD;               // 65536

  prep_kernel<<<(QD * KD + KD * KD + 255) / 256, 256, 0, stream>>>(w_q, w_k, w_v, mt, wvb);
  fused_kernel<<<Bn / NR, 256, 0, stream>>>(query, kv, mt, wvb, gamma, beta, out);
}

// Round 4
// 290.833 us; speedup vs baseline: 1.0876x; 1.0340x over previous
//
#include <hip/hip_runtime.h>

#define QD 512
#define KD 64
#define NR 32     // rows per block
#define LDA 136   // lds_A row stride in shorts (128 + 8 pad)
#define LDT 68    // lds_t row stride in floats (64 + 4 pad) — aliases lds_A (same bytes)
#define LDU 72    // lds_u row stride in shorts (64 + 8 pad)

typedef __attribute__((ext_vector_type(8))) short short8;
typedef __attribute__((ext_vector_type(4))) float f32x4;
typedef __attribute__((ext_vector_type(4))) unsigned short u16x4;

static __device__ __forceinline__ unsigned short f2bf(float f) {
  unsigned u = __builtin_bit_cast(unsigned, f);
  u += 0x7FFFu + ((u >> 16) & 1u);   // round-to-nearest-even
  return (unsigned short)(u >> 16);
}
static __device__ __forceinline__ float bf2f(unsigned short s) {
  return __builtin_bit_cast(float, (unsigned)s << 16);
}
static __device__ __forceinline__ short8 pack8(f32x4 a, f32x4 b) {
  short8 r;
  r[0] = (short)f2bf(a[0]); r[1] = (short)f2bf(a[1]);
  r[2] = (short)f2bf(a[2]); r[3] = (short)f2bf(a[3]);
  r[4] = (short)f2bf(b[0]); r[5] = (short)f2bf(b[1]);
  r[6] = (short)f2bf(b[2]); r[7] = (short)f2bf(b[3]);
  return r;
}

// Prep: M^T[c][d] = sum_e w_q[e,d]*w_k[e,c]  (bf16), plus w_v cast to bf16.
__global__ __launch_bounds__(256) void prep_kernel(
    const float* __restrict__ w_q, const float* __restrict__ w_k,
    const float* __restrict__ w_v, unsigned short* __restrict__ mt,
    unsigned short* __restrict__ wvb) {
  const int tid = (int)(blockIdx.x * 256 + threadIdx.x);
  if (tid < QD * KD) {
    const int c = tid >> 9;      // 0..63
    const int d = tid & 511;     // 0..511
    float acc = 0.f;
#pragma unroll 8
    for (int e = 0; e < 64; ++e)
      acc = fmaf(w_q[e * QD + d], w_k[e * KD + c], acc);
    mt[c * QD + d] = f2bf(acc);
  } else {
    const int i = tid - QD * KD;
    if (i < KD * KD) wvb[i] = f2bf(w_v[i]);
  }
}

// NOTE: no min-waves clause. Round 2/3 evidence: __launch_bounds__(256,6)
// made the allocator collapse to VGPR_Count=40 and spill ~40 MB to scratch
// (WRITE_SIZE 57 MB vs 16.8 MB output). Round 1 with a bare (256) allocated
// 84 regs with ~zero spill. Keep pressure ~90 via 2x4 bfrag double-buffer.
__global__ __launch_bounds__(256) void fused_kernel(
    const float* __restrict__ query,
    const float* __restrict__ kv,
    const unsigned short* __restrict__ mt,
    const unsigned short* __restrict__ wvb,
    const float* __restrict__ gamma,
    const float* __restrict__ beta,
    float* __restrict__ out) {
  // lds_A (bf16 query tile) and lds_t (fp32 t/o tile) have disjoint lifetimes
  // separated by __syncthreads — alias them. 8704 B each.
  __shared__ char shbuf[NR * LDA * 2];
  unsigned short* lds_A = (unsigned short*)shbuf;
  float* lds_t = (float*)shbuf;
  __shared__ unsigned short lds_u[NR * LDU];   // 4608 B. Total LDS = 13312 B.

  const int tid  = (int)threadIdx.x;
  const int w    = tid >> 6;       // wave 0..3 -> col-tile of 16
  const int l    = tid & 63;
  const int m    = l & 15;
  const int quad = l >> 4;
  const long b0  = (long)blockIdx.x * NR;

  // ---- B fragments of M^T: double-buffered 4-at-a-time along K chunks ----
  const unsigned short* mrow = mt + (w * 16 + m) * QD + quad * 8;
  short8 bf_cur[4], bf_nxt[4];
#pragma unroll
  for (int ks = 0; ks < 4; ++ks)
    bf_cur[ks] = *(const short8*)(mrow + ks * 32);

  f32x4 acc[2];
  acc[0] = (f32x4){0.f, 0.f, 0.f, 0.f};
  acc[1] = (f32x4){0.f, 0.f, 0.f, 0.f};

  // ---- GEMM1: t = query_tile @ M, K=512 in 4 chunks of 128, prefetched ----
  const int srow = tid >> 3;   // 0..31
  const int cseg = tid & 7;    // 0..7, 16 k's each per chunk
  const float* qbase = query + (b0 + srow) * QD + cseg * 16;
  unsigned short* abase = lds_A + srow * LDA + cseg * 16;

  f32x4 stg[4];
#pragma unroll
  for (int i = 0; i < 4; ++i) stg[i] = *(const f32x4*)(qbase + i * 4);

#pragma unroll
  for (int kc = 0; kc < 4; ++kc) {
#pragma unroll
    for (int i = 0; i < 4; ++i)
      *(u16x4*)(abase + i * 4) = (u16x4){f2bf(stg[i][0]), f2bf(stg[i][1]),
                                         f2bf(stg[i][2]), f2bf(stg[i][3])};
    __syncthreads();
    if (kc < 3) {
      const float* nq = qbase + (kc + 1) * 128;
#pragma unroll
      for (int i = 0; i < 4; ++i) stg[i] = *(const f32x4*)(nq + i * 4);
      const unsigned short* mn = mrow + (kc + 1) * 128;
#pragma unroll
      for (int ks = 0; ks < 4; ++ks)
        bf_nxt[ks] = *(const short8*)(mn + ks * 32);
    }
#pragma unroll
    for (int ks2 = 0; ks2 < 4; ++ks2) {
#pragma unroll
      for (int rt = 0; rt < 2; ++rt) {
        short8 af = *(const short8*)(lds_A + (rt * 16 + m) * LDA + ks2 * 32 + quad * 8);
        acc[rt] = __builtin_amdgcn_mfma_f32_16x16x32_bf16(af, bf_cur[ks2],
                                                          acc[rt], 0, 0, 0);
      }
    }
    __syncthreads();
    if (kc < 3) {
#pragma unroll
      for (int ks = 0; ks < 4; ++ks) bf_cur[ks] = bf_nxt[ks];
    }
  }

  // ---- write t to LDS (C layout: col=lane&15, row=quad*4+reg) ----
  // Safe to alias lds_A: last MFMA read is before the final barrier above.
#pragma unroll
  for (int rt = 0; rt < 2; ++rt)
#pragma unroll
    for (int r2 = 0; r2 < 4; ++r2)
      lds_t[(rt * 16 + quad * 4 + r2) * LDT + w * 16 + m] = acc[rt][r2];
  __syncthreads();

  // ---- per-row attention: 8 threads per row, 8 dims per thread ----
  const int rl = w * 8 + (l >> 3);   // row 0..31
  const int o8 = l & 7;              // dim segment
  const int db = o8 * 8;             // dim base
  const long brow = b0 + rl;

  const float* tp = lds_t + rl * LDT + db;
  f32x4 tv0 = ((const f32x4*)tp)[0];
  f32x4 tv1 = ((const f32x4*)tp)[1];

  float s[8];
  short8 kvb[8];
#pragma unroll
  for (int n = 0; n < 8; ++n) {
    const float* kp = kv + (brow * 8 + n) * 64 + db;
    f32x4 k0 = ((const f32x4*)kp)[0];
    f32x4 k1 = ((const f32x4*)kp)[1];
    f32x4 d = tv0 * k0 + tv1 * k1;
    s[n] = d[0] + d[1] + d[2] + d[3];
    kvb[n] = pack8(k0, k1);           // hold kv as bf16 for the u pass
  }
#pragma unroll
  for (int n = 0; n < 8; ++n) {       // reduce partials across the 8 dim-lanes
    s[n] += __shfl_xor(s[n], 1, 64);
    s[n] += __shfl_xor(s[n], 2, 64);
    s[n] += __shfl_xor(s[n], 4, 64);
  }
  float mx = s[0];
#pragma unroll
  for (int n = 1; n < 8; ++n) mx = fmaxf(mx, s[n]);
  float ev[8];
  float esum = 0.f;
#pragma unroll
  for (int n = 0; n < 8; ++n) { ev[n] = __expf((s[n] - mx) * 0.125f); esum += ev[n]; }
  const float rinv = 1.0f / esum;

  f32x4 u0 = {0.f, 0.f, 0.f, 0.f}, u1 = u0;
#pragma unroll
  for (int n = 0; n < 8; ++n) {
    const float a = ev[n];
    short8 p = kvb[n];
    u0 += a * (f32x4){bf2f((unsigned short)p[0]), bf2f((unsigned short)p[1]),
                      bf2f((unsigned short)p[2]), bf2f((unsigned short)p[3])};
    u1 += a * (f32x4){bf2f((unsigned short)p[4]), bf2f((unsigned short)p[5]),
                      bf2f((unsigned short)p[6]), bf2f((unsigned short)p[7])};
  }
  u0 *= rinv; u1 *= rinv;
  *(short8*)(lds_u + rl * LDU + db) = pack8(u0, u1);
  __syncthreads();

  // ---- GEMM2: o = u @ w_v^T (K=64, 2 MFMA k-steps) ----
  short8 wvf0 = *(const short8*)(wvb + (w * 16 + m) * 64 + quad * 8);
  short8 wvf1 = *(const short8*)(wvb + (w * 16 + m) * 64 + 32 + quad * 8);
  f32x4 o[2];
  o[0] = (f32x4){0.f, 0.f, 0.f, 0.f};
  o[1] = (f32x4){0.f, 0.f, 0.f, 0.f};
#pragma unroll
  for (int rt = 0; rt < 2; ++rt) {
    short8 a0 = *(const short8*)(lds_u + (rt * 16 + m) * LDU + quad * 8);
    o[rt] = __builtin_amdgcn_mfma_f32_16x16x32_bf16(a0, wvf0, o[rt], 0, 0, 0);
    short8 a1 = *(const short8*)(lds_u + (rt * 16 + m) * LDU + 32 + quad * 8);
    o[rt] = __builtin_amdgcn_mfma_f32_16x16x32_bf16(a1, wvf1, o[rt], 0, 0, 0);
  }
  // write o into lds_t (safe: all tv reads completed before the u barrier)
#pragma unroll
  for (int rt = 0; rt < 2; ++rt)
#pragma unroll
    for (int r2 = 0; r2 < 4; ++r2)
      lds_t[(rt * 16 + quad * 4 + r2) * LDT + w * 16 + m] = o[rt][r2];
  __syncthreads();

  // ---- LayerNorm over 64 dims (8 lanes per row) ----
  const float* op = lds_t + rl * LDT + db;
  f32x4 x0 = ((const f32x4*)op)[0];
  f32x4 x1 = ((const f32x4*)op)[1];
  f32x4 sv = x0 + x1;
  f32x4 sq = x0 * x0 + x1 * x1;
  float s1 = sv[0] + sv[1] + sv[2] + sv[3];
  float s2 = sq[0] + sq[1] + sq[2] + sq[3];
  s1 += __shfl_xor(s1, 1, 64); s1 += __shfl_xor(s1, 2, 64); s1 += __shfl_xor(s1, 4, 64);
  s2 += __shfl_xor(s2, 1, 64); s2 += __shfl_xor(s2, 2, 64); s2 += __shfl_xor(s2, 4, 64);
  const float mu   = s1 * 0.015625f;
  const float var  = s2 * 0.015625f - mu * mu;
  const float rstd = rsqrtf(var + 1e-5f);
  const float* gp = gamma + db;
  const float* bp = beta + db;
  float* dst = out + brow * 64 + db;
  {
    f32x4 g0 = ((const f32x4*)gp)[0], g1 = ((const f32x4*)gp)[1];
    f32x4 e0 = ((const f32x4*)bp)[0], e1 = ((const f32x4*)bp)[1];
    ((f32x4*)dst)[0] = (x0 - mu) * rstd * g0 + e0;
    ((f32x4*)dst)[1] = (x1 - mu) * rstd * g1 + e1;
  }
}

extern "C" void kernel_launch(void* const* d_in, const int* in_sizes, int n_in,
                              void* d_out, int out_size, void* d_ws, size_t ws_size,
                              hipStream_t stream) {
  const float* query = (const float*)d_in[0];
  const float* kv    = (const float*)d_in[1];
  const float* w_q   = (const float*)d_in[2];
  const float* w_k   = (const float*)d_in[3];
  const float* w_v   = (const float*)d_in[4];
  const float* gamma = (const float*)d_in[5];
  const float* beta  = (const float*)d_in[6];
  float* out = (float*)d_out;

  unsigned short* mt  = (unsigned short*)d_ws;   // 512*64 bf16
  unsigned short* wvb = mt + QD * KD;            // 64*64 bf16

  const int Bn = in_sizes[0] / QD;               // 65536

  prep_kernel<<<(QD * KD + KD * KD + 255) / 256, 256, 0, stream>>>(w_q, w_k, w_v, mt, wvb);
  fused_kernel<<<Bn / NR, 256, 0, stream>>>(query, kv, mt, wvb, gamma, beta, out);
}